// Round 4
// baseline (1260.363 us; speedup 1.0000x reference)
//
#include <hip/hip_runtime.h>

// ---------------- constants ----------------
#define M_TOK 18464      // 32*577 tokens
#define TSEQ  577
#define NBATCH 32
#define NH    16
#define HD    64
#define DIMM  1024
#define HIDD  4096

typedef __attribute__((ext_vector_type(4))) float f32x4;
typedef __attribute__((ext_vector_type(8))) short bf8;   // 8 bf16 in 4 VGPRs (MFMA A/B frag)
typedef __attribute__((ext_vector_type(8))) short s8v;
typedef __attribute__((ext_vector_type(4))) short s4v;

__device__ __forceinline__ short f2bf(float f) {
  union { float f; unsigned u; } c; c.f = f;
  unsigned u = c.u;
  unsigned r = (u + 0x7fffu + ((u >> 16) & 1u)) >> 16;  // RNE
  return (short)r;
}

// async global->LDS, 16B per lane; dest = wave-uniform base + lane*16
__device__ __forceinline__ void gld_lds16(const short* g, short* l) {
  __builtin_amdgcn_global_load_lds(
      (const __attribute__((address_space(1))) unsigned int*)g,
      (__attribute__((address_space(3))) unsigned int*)l, 16, 0, 0);
}

#define MFMA16(a, b, c) __builtin_amdgcn_mfma_f32_16x16x32_bf16(a, b, c, 0, 0, 0)

// ---------------- weight convert + transpose: W[K][N] f32 -> WT[N][K] bf16 ----------------
__global__ __launch_bounds__(256) void conv_t_kernel(const float* __restrict__ W,
                                                     short* __restrict__ WT,
                                                     int K, int N) {
  __shared__ short tile[32][33];
  int bx = blockIdx.x;  // n tile
  int by = blockIdx.y;  // k tile
  int t = threadIdx.x;
  int c = t & 31, r = t >> 5;  // 32 cols x 8 rows
#pragma unroll
  for (int rr = r; rr < 32; rr += 8)
    tile[rr][c] = f2bf(W[(size_t)(by * 32 + rr) * N + bx * 32 + c]);
  __syncthreads();
#pragma unroll
  for (int rr = r; rr < 32; rr += 8)
    WT[(size_t)(bx * 32 + rr) * K + by * 32 + c] = tile[c][rr];
}

// ---------------- layernorm: f32 [M][1024] -> bf16 [M][1024] ----------------
__global__ __launch_bounds__(256) void ln_kernel(const float* __restrict__ x,
                                                 const float* __restrict__ g,
                                                 const float* __restrict__ b,
                                                 short* __restrict__ out) {
  __shared__ float red[4];
  int row = blockIdx.x;
  int t = threadIdx.x, w = t >> 6, l = t & 63;
  const float4* xr = (const float4*)(x + (size_t)row * DIMM);
  float4 v = xr[t];
  float s1 = v.x + v.y + v.z + v.w;
#pragma unroll
  for (int m = 1; m < 64; m <<= 1) s1 += __shfl_xor(s1, m);
  if (l == 0) red[w] = s1;
  __syncthreads();
  float mu = (red[0] + red[1] + red[2] + red[3]) * (1.0f / 1024.0f);
  float dx = v.x - mu, dy = v.y - mu, dz = v.z - mu, dw = v.w - mu;
  float s2 = dx * dx + dy * dy + dz * dz + dw * dw;
#pragma unroll
  for (int m = 1; m < 64; m <<= 1) s2 += __shfl_xor(s2, m);
  __syncthreads();
  if (l == 0) red[w] = s2;
  __syncthreads();
  float var = (red[0] + red[1] + red[2] + red[3]) * (1.0f / 1024.0f);
  float rs = rsqrtf(var + 1e-6f);
  const float4* g4 = (const float4*)g;
  const float4* b4 = (const float4*)b;
  float4 gv = g4[t], bv = b4[t];
  s4v o;
  o[0] = f2bf(dx * rs * gv.x + bv.x);
  o[1] = f2bf(dy * rs * gv.y + bv.y);
  o[2] = f2bf(dz * rs * gv.z + bv.z);
  o[3] = f2bf(dw * rs * gv.w + bv.w);
  *(s4v*)(out + (size_t)row * DIMM + t * 4) = o;
}

// ---------------- GEMM: C[M][N] = A[M][K](bf16, lda) @ BT[N][K](bf16, ldb)^T + bias ----------
// EPI 0: out bf16 = C + bias            (QKV)
// EPI 1: out f32  = C + bias + res      (proj: res=x; fc2 chunk0: res=out in-place)
// EPI 2: out bf16 = gelu_exact(C+bias)  (fc1)
// EPI 3: out f32 += C                   (fc2 chunk1 accumulate, no bias)
template <int EPI>
__global__ __launch_bounds__(256, 2) void gemm_kernel(const short* __restrict__ A,
                                                      const short* __restrict__ BT,
                                                      const float* __restrict__ bias,
                                                      const float* res, short* outh,
                                                      float* outf, int M, int K, int N,
                                                      int lda, int ldb, int ntn) {
  __shared__ short lA[128 * 64];
  __shared__ short lB[128 * 64];
  int bid = blockIdx.x;
  int tm = bid / ntn, tn = bid % ntn;
  int m0 = tm * 128, n0 = tn * 128;
  int t = threadIdx.x, w = t >> 6, l = t & 63;
  int wm = w >> 1, wn = w & 1;  // 2x2 waves, each 64x64 out
  f32x4 acc[4][4] = {};

  for (int k0 = 0; k0 < K; k0 += 64) {
    __syncthreads();  // protect LDS from previous iteration's readers
#pragma unroll
    for (int i = 0; i < 4; i++) {  // A tile: 128x64 bf16 = 1024 chunks of 16B
      int c = i * 256 + t;
      int row = c >> 3, c8 = c & 7;
      int mg = m0 + row;
      if (mg > M - 1) mg = M - 1;
      gld_lds16(A + (size_t)mg * lda + k0 + c8 * 8, &lA[(i * 256 + w * 64) * 8]);
    }
#pragma unroll
    for (int i = 0; i < 4; i++) {  // B tile
      int c = i * 256 + t;
      int row = c >> 3, c8 = c & 7;
      gld_lds16(BT + (size_t)(n0 + row) * ldb + k0 + c8 * 8, &lB[(i * 256 + w * 64) * 8]);
    }
    __syncthreads();  // drains vmcnt
#pragma unroll
    for (int ks = 0; ks < 2; ++ks) {
      bf8 af[4], bfr[4];
#pragma unroll
      for (int i = 0; i < 4; i++)
        af[i] = *(const bf8*)&lA[(wm * 64 + i * 16 + (l & 15)) * 64 + ks * 32 + (l >> 4) * 8];
#pragma unroll
      for (int j = 0; j < 4; j++)
        bfr[j] = *(const bf8*)&lB[(wn * 64 + j * 16 + (l & 15)) * 64 + ks * 32 + (l >> 4) * 8];
#pragma unroll
      for (int i = 0; i < 4; i++)
#pragma unroll
        for (int j = 0; j < 4; j++) acc[i][j] = MFMA16(af[i], bfr[j], acc[i][j]);
    }
  }

  // epilogue: C/D layout col=lane&15, row=4*(lane>>4)+reg (HW-verified)
#pragma unroll
  for (int jf = 0; jf < 4; ++jf) {
    int col = n0 + wn * 64 + jf * 16 + (l & 15);
    float bz = (EPI == 3) ? 0.f : bias[col];
#pragma unroll
    for (int ifr = 0; ifr < 4; ++ifr) {
      int rbase = m0 + wm * 64 + ifr * 16 + (l >> 4) * 4;
#pragma unroll
      for (int q = 0; q < 4; ++q) {
        int row = rbase + q;
        if (row < M) {
          float v = acc[ifr][jf][q] + bz;
          size_t idx = (size_t)row * N + col;
          if constexpr (EPI == 0) {
            outh[idx] = f2bf(v);
          } else if constexpr (EPI == 1) {
            outf[idx] = v + res[idx];
          } else if constexpr (EPI == 2) {
            float gl = 0.5f * v * (1.0f + erff(v * 0.70710678118f));
            outh[idx] = f2bf(gl);
          } else {
            outf[idx] += v;
          }
        }
      }
    }
  }
}

// ---------------- flash attention ----------------
// qkv bf16 [M][3072] (per token: q[16][64] k v), out bf16 [M][1024]
__global__ __launch_bounds__(256, 2) void attn_kernel(const short* __restrict__ qkv,
                                                      short* __restrict__ aout) {
  __shared__ short lQ[64 * 64];
  __shared__ short lK[64 * 64];
  __shared__ short lVt[64 * 64];      // [d][key]
  __shared__ short lP[4 * 16 * 64];   // per-wave [qrow][key]
  int qt = blockIdx.x;   // 0..9
  int h = blockIdx.y;    // 0..15
  int b = blockIdx.z;    // 0..31
  int t = threadIdx.x, w = t >> 6, l = t & 63;
  int m0 = qt * 64;

  // stage Q tile (64 rows x 64 d)
#pragma unroll
  for (int i = 0; i < 2; i++) {
    int c = i * 256 + t;
    int row = c >> 3, c8 = c & 7;
    int tok = m0 + row;
    if (tok >= TSEQ) tok = TSEQ - 1;
    gld_lds16(qkv + (size_t)(b * TSEQ + tok) * 3072 + h * 64 + c8 * 8,
              &lQ[(i * 256 + w * 64) * 8]);
  }
  __syncthreads();
  bf8 qf[2];
  qf[0] = *(const bf8*)&lQ[(w * 16 + (l & 15)) * 64 + 0 + (l >> 4) * 8];
  qf[1] = *(const bf8*)&lQ[(w * 16 + (l & 15)) * 64 + 32 + (l >> 4) * 8];

  float m_run[4], l_run[4], p[4][4];
  f32x4 o_acc[4] = {};
#pragma unroll
  for (int q = 0; q < 4; q++) { m_run[q] = -1e30f; l_run[q] = 0.f; }

  for (int kt = 0; kt < 10; ++kt) {
    __syncthreads();  // previous iteration's LDS readers done
    // stage K tile
#pragma unroll
    for (int i = 0; i < 2; i++) {
      int c = i * 256 + t;
      int row = c >> 3, c8 = c & 7;
      int tok = kt * 64 + row;
      if (tok >= TSEQ) tok = TSEQ - 1;
      gld_lds16(qkv + (size_t)(b * TSEQ + tok) * 3072 + 1024 + h * 64 + c8 * 8,
                &lK[(i * 256 + w * 64) * 8]);
    }
    // stage V transposed: [d][key]
#pragma unroll
    for (int i = 0; i < 2; i++) {
      int c = i * 256 + t;
      int row = c >> 3, c8 = c & 7;
      int tok = kt * 64 + row;
      if (tok >= TSEQ) tok = TSEQ - 1;
      s8v vv = *(const s8v*)(qkv + (size_t)(b * TSEQ + tok) * 3072 + 2048 + h * 64 + c8 * 8);
#pragma unroll
      for (int j = 0; j < 8; j++) lVt[(c8 * 8 + j) * 64 + row] = vv[j];
    }
    __syncthreads();  // K,V ready

    // S = Q K^T * scale (per wave: 16 q-rows x 64 keys)
    f32x4 s[4];
#pragma unroll
    for (int nf = 0; nf < 4; ++nf) {
      f32x4 a = {};
#pragma unroll
      for (int ks = 0; ks < 2; ++ks) {
        bf8 kf = *(const bf8*)&lK[(nf * 16 + (l & 15)) * 64 + ks * 32 + (l >> 4) * 8];
        a = MFMA16(qf[ks], kf, a);
      }
      int key = kt * 64 + nf * 16 + (l & 15);
      bool valid = key < TSEQ;
#pragma unroll
      for (int q = 0; q < 4; q++) s[nf][q] = valid ? a[q] * 0.125f : -1e30f;
    }
    // online softmax (rows live across 16-lane groups)
#pragma unroll
    for (int q = 0; q < 4; q++) {
      float rm = fmaxf(fmaxf(s[0][q], s[1][q]), fmaxf(s[2][q], s[3][q]));
#pragma unroll
      for (int mm = 1; mm < 16; mm <<= 1) rm = fmaxf(rm, __shfl_xor(rm, mm));
      float mnew = fmaxf(m_run[q], rm);
      float corr = __expf(m_run[q] - mnew);
      m_run[q] = mnew;
      float rs = 0.f;
#pragma unroll
      for (int nf = 0; nf < 4; nf++) {
        float pv = __expf(s[nf][q] - mnew);
        p[nf][q] = pv;
        rs += pv;
      }
#pragma unroll
      for (int mm = 1; mm < 16; mm <<= 1) rs += __shfl_xor(rs, mm);
      l_run[q] = l_run[q] * corr + rs;
#pragma unroll
      for (int df = 0; df < 4; df++) o_acc[df][q] *= corr;
    }
    // P -> LDS (C-layout write, A-layout read; self-consistent k-mapping)
#pragma unroll
    for (int nf = 0; nf < 4; nf++)
#pragma unroll
      for (int q = 0; q < 4; q++)
        lP[w * 1024 + ((l >> 4) * 4 + q) * 64 + nf * 16 + (l & 15)] = f2bf(p[nf][q]);
    __syncthreads();
    // O += P V
#pragma unroll
    for (int ks = 0; ks < 2; ++ks) {
      bf8 pf = *(const bf8*)&lP[w * 1024 + (l & 15) * 64 + ks * 32 + (l >> 4) * 8];
#pragma unroll
      for (int df = 0; df < 4; df++) {
        bf8 vf = *(const bf8*)&lVt[(df * 16 + (l & 15)) * 64 + ks * 32 + (l >> 4) * 8];
        o_acc[df] = MFMA16(pf, vf, o_acc[df]);
      }
    }
  }
  // final normalize + store
#pragma unroll
  for (int df = 0; df < 4; df++) {
#pragma unroll
    for (int q = 0; q < 4; q++) {
      int tq = m0 + w * 16 + (l >> 4) * 4 + q;
      if (tq < TSEQ) {
        float val = o_acc[df][q] / l_run[q];
        aout[(size_t)(b * TSEQ + tq) * DIMM + h * 64 + df * 16 + (l & 15)] = f2bf(val);
      }
    }
  }
}

// ---------------- launch ----------------
extern "C" void kernel_launch(void* const* d_in, const int* in_sizes, int n_in,
                              void* d_out, int out_size, void* d_ws, size_t ws_size,
                              hipStream_t stream) {
  const float* x      = (const float*)d_in[0];
  const float* ln1_g  = (const float*)d_in[1];
  const float* ln1_b  = (const float*)d_in[2];
  const float* qkv_w  = (const float*)d_in[3];
  const float* qkv_b  = (const float*)d_in[4];
  const float* proj_w = (const float*)d_in[5];
  const float* proj_b = (const float*)d_in[6];
  const float* ln2_g  = (const float*)d_in[7];
  const float* ln2_b  = (const float*)d_in[8];
  const float* fc1_w  = (const float*)d_in[9];
  const float* fc1_b  = (const float*)d_in[10];
  const float* fc2_w  = (const float*)d_in[11];
  const float* fc2_b  = (const float*)d_in[12];
  float* out = (float*)d_out;

  // ---- workspace layout (peak 176.4 MB, buffers reused serially) ----
  // weights: 25.2 MB | bufA: 37.8 MB (ln1 -> attn_out -> ln2) | bufB: 113.4 MB (qkv -> h chunks)
  const size_t REQ = (size_t)(12582912 + (size_t)M_TOK * 1024 + (size_t)M_TOK * 3072) * 2;
  if (ws_size < REQ) return;  // diagnostic: clean absmax-fail instead of OOB abort

  short* w_qkv  = (short*)d_ws;                      // [3072][1024]
  short* w_proj = w_qkv + (size_t)3072 * 1024;       // [1024][1024]
  short* w_fc1  = w_proj + (size_t)1024 * 1024;      // [4096][1024]
  short* w_fc2  = w_fc1 + (size_t)4096 * 1024;       // [1024][4096]
  short* bufA   = w_fc2 + (size_t)1024 * 4096;       // [M][1024]
  short* bufB   = bufA + (size_t)M_TOK * 1024;       // [M][3072]

  dim3 blk(256);
  // weight transpose+convert
  conv_t_kernel<<<dim3(3072 / 32, 1024 / 32), blk, 0, stream>>>(qkv_w, w_qkv, 1024, 3072);
  conv_t_kernel<<<dim3(1024 / 32, 1024 / 32), blk, 0, stream>>>(proj_w, w_proj, 1024, 1024);
  conv_t_kernel<<<dim3(4096 / 32, 1024 / 32), blk, 0, stream>>>(fc1_w, w_fc1, 1024, 4096);
  conv_t_kernel<<<dim3(1024 / 32, 4096 / 32), blk, 0, stream>>>(fc2_w, w_fc2, 4096, 1024);
  // LN1: x -> bufA
  ln_kernel<<<M_TOK, blk, 0, stream>>>(x, ln1_g, ln1_b, bufA);
  // QKV: bufA @ w_qkv^T -> bufB
  gemm_kernel<0><<<145 * 24, blk, 0, stream>>>(bufA, w_qkv, qkv_b, nullptr, bufB, nullptr,
                                               M_TOK, 1024, 3072, 1024, 1024, 24);
  // attention: bufB -> bufA
  attn_kernel<<<dim3(10, NH, NBATCH), blk, 0, stream>>>(bufB, bufA);
  // proj + residual(x) -> out (x1)
  gemm_kernel<1><<<145 * 8, blk, 0, stream>>>(bufA, w_proj, proj_b, x, nullptr, out,
                                              M_TOK, 1024, 1024, 1024, 1024, 8);
  // LN2 on x1 -> bufA
  ln_kernel<<<M_TOK, blk, 0, stream>>>(out, ln2_g, ln2_b, bufA);
  // FFN in 2 hidden-dim chunks of 2048 (h chunk lives in bufB)
  for (int c = 0; c < 2; ++c) {
    // FC1 chunk + GELU: bufA @ w_fc1[c*2048 : +2048]^T -> bufB  [M][2048]
    gemm_kernel<2><<<145 * 16, blk, 0, stream>>>(bufA, w_fc1 + (size_t)c * 2048 * 1024,
                                                 fc1_b + c * 2048, nullptr, bufB, nullptr,
                                                 M_TOK, 1024, 2048, 1024, 1024, 16);
    // FC2 chunk: out (+)= bufB @ w_fc2[:, c*2048 : +2048]^T (+ bias + res on chunk 0)
    if (c == 0) {
      gemm_kernel<1><<<145 * 8, blk, 0, stream>>>(bufB, w_fc2 + (size_t)c * 2048, fc2_b, out,
                                                  nullptr, out, M_TOK, 2048, 1024, 2048, 4096, 8);
    } else {
      gemm_kernel<3><<<145 * 8, blk, 0, stream>>>(bufB, w_fc2 + (size_t)c * 2048, fc2_b, out,
                                                  nullptr, out, M_TOK, 2048, 1024, 2048, 4096, 8);
    }
  }
}

// Round 5
// 1146.399 us; speedup vs baseline: 1.0994x; 1.0994x over previous
//
#include <hip/hip_runtime.h>

// ---------------- constants ----------------
#define M_TOK 18464      // 32*577 tokens
#define TSEQ  577
#define NBATCH 32
#define NH    16
#define HD    64
#define DIMM  1024
#define HIDD  4096

typedef __attribute__((ext_vector_type(4))) float f32x4;
typedef __attribute__((ext_vector_type(8))) short bf8;   // 8 bf16 in 4 VGPRs (MFMA A/B frag)
typedef __attribute__((ext_vector_type(8))) short s8v;
typedef __attribute__((ext_vector_type(4))) short s4v;   // 64-bit: tr-read result

__device__ __forceinline__ short f2bf(float f) {
  union { float f; unsigned u; } c; c.f = f;
  unsigned u = c.u;
  unsigned r = (u + 0x7fffu + ((u >> 16) & 1u)) >> 16;  // RNE
  return (short)r;
}

// async global->LDS, 16B per lane; dest = wave-uniform base + lane*16
__device__ __forceinline__ void gld_lds16(const short* g, short* l) {
  __builtin_amdgcn_global_load_lds(
      (const __attribute__((address_space(1))) unsigned int*)g,
      (__attribute__((address_space(3))) unsigned int*)l, 16, 0, 0);
}

#define MFMA16(a, b, c) __builtin_amdgcn_mfma_f32_16x16x32_bf16(a, b, c, 0, 0, 0)

// ---------------- weight convert + transpose: W[K][N] f32 -> WT[N][K] bf16 ----------------
__global__ __launch_bounds__(256) void conv_t_kernel(const float* __restrict__ W,
                                                     short* __restrict__ WT,
                                                     int K, int N) {
  __shared__ short tile[32][33];
  int bx = blockIdx.x;  // n tile
  int by = blockIdx.y;  // k tile
  int t = threadIdx.x;
  int c = t & 31, r = t >> 5;  // 32 cols x 8 rows
#pragma unroll
  for (int rr = r; rr < 32; rr += 8)
    tile[rr][c] = f2bf(W[(size_t)(by * 32 + rr) * N + bx * 32 + c]);
  __syncthreads();
#pragma unroll
  for (int rr = r; rr < 32; rr += 8)
    WT[(size_t)(bx * 32 + rr) * K + by * 32 + c] = tile[c][rr];
}

// ---------------- layernorm: f32 [M][1024] -> bf16 [M][1024] ----------------
__global__ __launch_bounds__(256) void ln_kernel(const float* __restrict__ x,
                                                 const float* __restrict__ g,
                                                 const float* __restrict__ b,
                                                 short* __restrict__ out) {
  __shared__ float red[4];
  int row = blockIdx.x;
  int t = threadIdx.x, w = t >> 6, l = t & 63;
  const float4* xr = (const float4*)(x + (size_t)row * DIMM);
  float4 v = xr[t];
  float s1 = v.x + v.y + v.z + v.w;
#pragma unroll
  for (int m = 1; m < 64; m <<= 1) s1 += __shfl_xor(s1, m);
  if (l == 0) red[w] = s1;
  __syncthreads();
  float mu = (red[0] + red[1] + red[2] + red[3]) * (1.0f / 1024.0f);
  float dx = v.x - mu, dy = v.y - mu, dz = v.z - mu, dw = v.w - mu;
  float s2 = dx * dx + dy * dy + dz * dz + dw * dw;
#pragma unroll
  for (int m = 1; m < 64; m <<= 1) s2 += __shfl_xor(s2, m);
  __syncthreads();
  if (l == 0) red[w] = s2;
  __syncthreads();
  float var = (red[0] + red[1] + red[2] + red[3]) * (1.0f / 1024.0f);
  float rs = rsqrtf(var + 1e-6f);
  const float4* g4 = (const float4*)g;
  const float4* b4 = (const float4*)b;
  float4 gv = g4[t], bv = b4[t];
  s4v o;
  o[0] = f2bf(dx * rs * gv.x + bv.x);
  o[1] = f2bf(dy * rs * gv.y + bv.y);
  o[2] = f2bf(dz * rs * gv.z + bv.z);
  o[3] = f2bf(dw * rs * gv.w + bv.w);
  *(s4v*)(out + (size_t)row * DIMM + t * 4) = o;
}

// ---------------- GEMM: C[M][N] = A[M][K](bf16, lda) @ BT[N][K](bf16, ldb)^T + bias ----------
// EPI 0: out bf16 = C + bias            (QKV)
// EPI 1: out f32  = C + bias + res      (proj: res=x; fc2 chunk0: res=out in-place)
// EPI 2: out bf16 = gelu_exact(C+bias)  (fc1)
// EPI 3: out f32 += C                   (fc2 chunk1 accumulate, no bias)
template <int EPI>
__global__ __launch_bounds__(256, 2) void gemm_kernel(const short* __restrict__ A,
                                                      const short* __restrict__ BT,
                                                      const float* __restrict__ bias,
                                                      const float* res, short* outh,
                                                      float* outf, int M, int K, int N,
                                                      int lda, int ldb, int ntn) {
  __shared__ short lA[128 * 64];
  __shared__ short lB[128 * 64];
  // XCD-aware bijective swizzle (gridDim.x % 8 == 0 by construction):
  // XCD x gets a contiguous chunk of tile-ids -> A-panel stays L2-resident per XCD.
  int bid0 = blockIdx.x;
  int cpx = gridDim.x >> 3;
  int bid = (bid0 & 7) * cpx + (bid0 >> 3);
  int tm = bid / ntn, tn = bid % ntn;
  int m0 = tm * 128, n0 = tn * 128;
  int t = threadIdx.x, w = t >> 6, l = t & 63;
  int wm = w >> 1, wn = w & 1;  // 2x2 waves, each 64x64 out
  f32x4 acc[4][4] = {};

  for (int k0 = 0; k0 < K; k0 += 64) {
    __syncthreads();  // protect LDS from previous iteration's readers
#pragma unroll
    for (int i = 0; i < 4; i++) {  // A tile: 128x64 bf16 = 1024 chunks of 16B
      int c = i * 256 + t;
      int row = c >> 3, c8 = c & 7;
      int mg = m0 + row;
      if (mg > M - 1) mg = M - 1;
      gld_lds16(A + (size_t)mg * lda + k0 + c8 * 8, &lA[(i * 256 + w * 64) * 8]);
    }
#pragma unroll
    for (int i = 0; i < 4; i++) {  // B tile
      int c = i * 256 + t;
      int row = c >> 3, c8 = c & 7;
      gld_lds16(BT + (size_t)(n0 + row) * ldb + k0 + c8 * 8, &lB[(i * 256 + w * 64) * 8]);
    }
    __syncthreads();  // drains vmcnt
#pragma unroll
    for (int ks = 0; ks < 2; ++ks) {
      bf8 af[4], bfr[4];
#pragma unroll
      for (int i = 0; i < 4; i++)
        af[i] = *(const bf8*)&lA[(wm * 64 + i * 16 + (l & 15)) * 64 + ks * 32 + (l >> 4) * 8];
#pragma unroll
      for (int j = 0; j < 4; j++)
        bfr[j] = *(const bf8*)&lB[(wn * 64 + j * 16 + (l & 15)) * 64 + ks * 32 + (l >> 4) * 8];
#pragma unroll
      for (int i = 0; i < 4; i++)
#pragma unroll
        for (int j = 0; j < 4; j++) acc[i][j] = MFMA16(af[i], bfr[j], acc[i][j]);
    }
  }

  // epilogue: C/D layout col=lane&15, row=4*(lane>>4)+reg (HW-verified)
#pragma unroll
  for (int jf = 0; jf < 4; ++jf) {
    int col = n0 + wn * 64 + jf * 16 + (l & 15);
    float bz = (EPI == 3) ? 0.f : bias[col];
#pragma unroll
    for (int ifr = 0; ifr < 4; ++ifr) {
      int rbase = m0 + wm * 64 + ifr * 16 + (l >> 4) * 4;
#pragma unroll
      for (int q = 0; q < 4; ++q) {
        int row = rbase + q;
        if (row < M) {
          float v = acc[ifr][jf][q] + bz;
          size_t idx = (size_t)row * N + col;
          if constexpr (EPI == 0) {
            outh[idx] = f2bf(v);
          } else if constexpr (EPI == 1) {
            outf[idx] = v + res[idx];
          } else if constexpr (EPI == 2) {
            float gl = 0.5f * v * (1.0f + erff(v * 0.70710678118f));
            outh[idx] = f2bf(gl);
          } else {
            outf[idx] += v;
          }
        }
      }
    }
  }
}

// ---------------- flash attention ----------------
// qkv bf16 [M][3072] (per token: q k v, 16 heads x 64), out bf16 [M][1024]
// grid (bh=512, qt=10): all q-tiles of one (b,h) share an XCD (K/V L2 locality).
// K in LDS with chunk^(key&7) XOR swizzle (pre-swizzled global source, linear dest).
// V in LDS in [k/4][d/16][4][16] subtiles; PV B-frags via ds_read_b64_tr_b16.
__global__ __launch_bounds__(256, 4) void attn_kernel(const short* __restrict__ qkv,
                                                      short* __restrict__ aout) {
  __shared__ short lK[64 * 64];
  __shared__ short lV[64 * 64];
  __shared__ short lP[4 * 16 * 64];
  int bh = blockIdx.x;
  int qt = blockIdx.y;
  int b = bh >> 4, h = bh & 15;
  int t = threadIdx.x, w = t >> 6, l = t & 63;
  int m0 = qt * 64;
  const size_t tokbase = (size_t)b * TSEQ;
  unsigned lvb = (unsigned)(uintptr_t)&lV[0];

  // Q fragments direct from global (read once per block)
  int tq0 = m0 + w * 16 + (l & 15); if (tq0 > TSEQ - 1) tq0 = TSEQ - 1;
  const short* qrow = qkv + (tokbase + tq0) * 3072 + h * 64;
  bf8 qf[2];
  qf[0] = *(const bf8*)(qrow + (l >> 4) * 8);
  qf[1] = *(const bf8*)(qrow + 32 + (l >> 4) * 8);

  float m_run[4], l_run[4], p[4][4];
  f32x4 o_acc[4] = {};
#pragma unroll
  for (int q = 0; q < 4; q++) { m_run[q] = -1e30f; l_run[q] = 0.f; }

  for (int kt = 0; kt < 10; ++kt) {
    __syncthreads();  // previous iteration's LDS readers done
    // stage K tile, chunk-swizzled: LDS pos L holds global chunk (L&7)^(key&7)
#pragma unroll
    for (int i = 0; i < 2; i++) {
      int L = i * 256 + t;
      int key = L >> 3;
      int cd = (L & 7) ^ (key & 7);
      int tok = kt * 64 + key; if (tok > TSEQ - 1) tok = TSEQ - 1;
      gld_lds16(qkv + (tokbase + tok) * 3072 + 1024 + h * 64 + cd * 8,
                &lK[(i * 256 + w * 64) * 8]);
    }
    // stage V tile into [k/4][d/16][4][16] subtiles (pre-permuted global source)
#pragma unroll
    for (int i = 0; i < 2; i++) {
      int L = i * 256 + t;
      int k = (L >> 5) * 4 + ((L >> 1) & 3);
      int c = ((L >> 3) & 3) * 2 + (L & 1);
      int tok = kt * 64 + k; if (tok > TSEQ - 1) tok = TSEQ - 1;
      gld_lds16(qkv + (tokbase + tok) * 3072 + 2048 + h * 64 + c * 8,
                &lV[(i * 256 + w * 64) * 8]);
    }
    __syncthreads();  // K,V ready

    // S = Q K^T * scale (per wave: 16 q-rows x 64 keys)
    f32x4 s[4];
    __builtin_amdgcn_s_setprio(1);
#pragma unroll
    for (int nf = 0; nf < 4; ++nf) {
      f32x4 a = {};
#pragma unroll
      for (int ks = 0; ks < 2; ++ks) {
        int keyrow = nf * 16 + (l & 15);
        int cp = (ks * 4 + (l >> 4)) ^ (keyrow & 7);
        bf8 kf = *(const bf8*)&lK[keyrow * 64 + cp * 8];
        a = MFMA16(qf[ks], kf, a);
      }
      int key = kt * 64 + nf * 16 + (l & 15);
      bool valid = key < TSEQ;
#pragma unroll
      for (int q = 0; q < 4; q++) s[nf][q] = valid ? a[q] * 0.125f : -1e30f;
    }
    __builtin_amdgcn_s_setprio(0);

    // online softmax (rows live across 16-lane groups)
#pragma unroll
    for (int q = 0; q < 4; q++) {
      float rm = fmaxf(fmaxf(s[0][q], s[1][q]), fmaxf(s[2][q], s[3][q]));
#pragma unroll
      for (int mm = 1; mm < 16; mm <<= 1) rm = fmaxf(rm, __shfl_xor(rm, mm));
      float mnew = fmaxf(m_run[q], rm);
      float corr = __expf(m_run[q] - mnew);
      m_run[q] = mnew;
      float rs = 0.f;
#pragma unroll
      for (int nf = 0; nf < 4; nf++) {
        float pv = __expf(s[nf][q] - mnew);
        p[nf][q] = pv;
        rs += pv;
      }
#pragma unroll
      for (int mm = 1; mm < 16; mm <<= 1) rs += __shfl_xor(rs, mm);
      l_run[q] = l_run[q] * corr + rs;
#pragma unroll
      for (int df = 0; df < 4; df++) o_acc[df][q] *= corr;
    }
    // P -> LDS (C-layout write, A-layout read; chunk^(qrow&7) swizzle both sides)
#pragma unroll
    for (int nf = 0; nf < 4; nf++)
#pragma unroll
      for (int q = 0; q < 4; q++) {
        int qr = (l >> 4) * 4 + q;
        int key = nf * 16 + (l & 15);
        int cp = (key >> 3) ^ (qr & 7);
        lP[w * 1024 + qr * 64 + cp * 8 + (key & 7)] = f2bf(p[nf][q]);
      }
    __syncthreads();

    // O += P V  (V^T b-frags via hardware transpose read)
#pragma unroll
    for (int ks = 0; ks < 2; ++ks) {
      int qr = l & 15;
      int cp = (ks * 4 + (l >> 4)) ^ (qr & 7);
      bf8 pf = *(const bf8*)&lP[w * 1024 + qr * 64 + cp * 8];
      unsigned kq0 = (unsigned)(ks * 8 + (l >> 4) * 2);
      unsigned abase = lvb + kq0 * 512u + (unsigned)(l & 15) * 8u;
      s4v ra0, ra1, rb0, rb1, rc0, rc1, rd0, rd1;
      asm volatile("ds_read_b64_tr_b16 %0, %1" : "=v"(ra0) : "v"(abase));
      asm volatile("ds_read_b64_tr_b16 %0, %1" : "=v"(ra1) : "v"(abase + 512u));
      asm volatile("ds_read_b64_tr_b16 %0, %1" : "=v"(rb0) : "v"(abase + 128u));
      asm volatile("ds_read_b64_tr_b16 %0, %1" : "=v"(rb1) : "v"(abase + 640u));
      asm volatile("ds_read_b64_tr_b16 %0, %1" : "=v"(rc0) : "v"(abase + 256u));
      asm volatile("ds_read_b64_tr_b16 %0, %1" : "=v"(rc1) : "v"(abase + 768u));
      asm volatile("ds_read_b64_tr_b16 %0, %1" : "=v"(rd0) : "v"(abase + 384u));
      asm volatile("ds_read_b64_tr_b16 %0, %1" : "=v"(rd1) : "v"(abase + 896u));
      asm volatile("s_waitcnt lgkmcnt(0)" ::: "memory");
      __builtin_amdgcn_sched_barrier(0);
      bf8 vfa = __builtin_shufflevector(ra0, ra1, 0, 1, 2, 3, 4, 5, 6, 7);
      bf8 vfb = __builtin_shufflevector(rb0, rb1, 0, 1, 2, 3, 4, 5, 6, 7);
      bf8 vfc = __builtin_shufflevector(rc0, rc1, 0, 1, 2, 3, 4, 5, 6, 7);
      bf8 vfd = __builtin_shufflevector(rd0, rd1, 0, 1, 2, 3, 4, 5, 6, 7);
      __builtin_amdgcn_s_setprio(1);
      o_acc[0] = MFMA16(pf, vfa, o_acc[0]);
      o_acc[1] = MFMA16(pf, vfb, o_acc[1]);
      o_acc[2] = MFMA16(pf, vfc, o_acc[2]);
      o_acc[3] = MFMA16(pf, vfd, o_acc[3]);
      __builtin_amdgcn_s_setprio(0);
    }
  }
  // final normalize + store
#pragma unroll
  for (int df = 0; df < 4; df++) {
#pragma unroll
    for (int q = 0; q < 4; q++) {
      int tq = m0 + w * 16 + (l >> 4) * 4 + q;
      if (tq < TSEQ) {
        float val = o_acc[df][q] / l_run[q];
        aout[(tokbase + tq) * DIMM + h * 64 + df * 16 + (l & 15)] = f2bf(val);
      }
    }
  }
}

// ---------------- launch ----------------
extern "C" void kernel_launch(void* const* d_in, const int* in_sizes, int n_in,
                              void* d_out, int out_size, void* d_ws, size_t ws_size,
                              hipStream_t stream) {
  const float* x      = (const float*)d_in[0];
  const float* ln1_g  = (const float*)d_in[1];
  const float* ln1_b  = (const float*)d_in[2];
  const float* qkv_w  = (const float*)d_in[3];
  const float* qkv_b  = (const float*)d_in[4];
  const float* proj_w = (const float*)d_in[5];
  const float* proj_b = (const float*)d_in[6];
  const float* ln2_g  = (const float*)d_in[7];
  const float* ln2_b  = (const float*)d_in[8];
  const float* fc1_w  = (const float*)d_in[9];
  const float* fc1_b  = (const float*)d_in[10];
  const float* fc2_w  = (const float*)d_in[11];
  const float* fc2_b  = (const float*)d_in[12];
  float* out = (float*)d_out;

  // ---- workspace layout (peak 176.4 MB, buffers reused serially) ----
  const size_t REQ = (size_t)(12582912 + (size_t)M_TOK * 1024 + (size_t)M_TOK * 3072) * 2;
  if (ws_size < REQ) return;  // diagnostic: clean absmax-fail instead of OOB abort

  short* w_qkv  = (short*)d_ws;                      // [3072][1024]
  short* w_proj = w_qkv + (size_t)3072 * 1024;       // [1024][1024]
  short* w_fc1  = w_proj + (size_t)1024 * 1024;      // [4096][1024]
  short* w_fc2  = w_fc1 + (size_t)4096 * 1024;       // [1024][4096]
  short* bufA   = w_fc2 + (size_t)1024 * 4096;       // [M][1024]
  short* bufB   = bufA + (size_t)M_TOK * 1024;       // [M][3072]

  dim3 blk(256);
  conv_t_kernel<<<dim3(3072 / 32, 1024 / 32), blk, 0, stream>>>(qkv_w, w_qkv, 1024, 3072);
  conv_t_kernel<<<dim3(1024 / 32, 1024 / 32), blk, 0, stream>>>(proj_w, w_proj, 1024, 1024);
  conv_t_kernel<<<dim3(4096 / 32, 1024 / 32), blk, 0, stream>>>(fc1_w, w_fc1, 1024, 4096);
  conv_t_kernel<<<dim3(1024 / 32, 4096 / 32), blk, 0, stream>>>(fc2_w, w_fc2, 4096, 1024);
  // LN1: x -> bufA
  ln_kernel<<<M_TOK, blk, 0, stream>>>(x, ln1_g, ln1_b, bufA);
  // QKV: bufA @ w_qkv^T -> bufB
  gemm_kernel<0><<<145 * 24, blk, 0, stream>>>(bufA, w_qkv, qkv_b, nullptr, bufB, nullptr,
                                               M_TOK, 1024, 3072, 1024, 1024, 24);
  // attention: bufB -> bufA
  attn_kernel<<<dim3(NBATCH * NH, 10), blk, 0, stream>>>(bufB, bufA);
  // proj + residual(x) -> out (x1)
  gemm_kernel<1><<<145 * 8, blk, 0, stream>>>(bufA, w_proj, proj_b, x, nullptr, out,
                                              M_TOK, 1024, 1024, 1024, 1024, 8);
  // LN2 on x1 -> bufA
  ln_kernel<<<M_TOK, blk, 0, stream>>>(out, ln2_g, ln2_b, bufA);
  // FFN in 2 hidden-dim chunks of 2048 (h chunk lives in bufB)
  for (int c = 0; c < 2; ++c) {
    gemm_kernel<2><<<145 * 16, blk, 0, stream>>>(bufA, w_fc1 + (size_t)c * 2048 * 1024,
                                                 fc1_b + c * 2048, nullptr, bufB, nullptr,
                                                 M_TOK, 1024, 2048, 1024, 1024, 16);
    if (c == 0) {
      gemm_kernel<1><<<145 * 8, blk, 0, stream>>>(bufB, w_fc2 + (size_t)c * 2048, fc2_b, out,
                                                  nullptr, out, M_TOK, 2048, 1024, 2048, 4096, 8);
    } else {
      gemm_kernel<3><<<145 * 8, blk, 0, stream>>>(bufB, w_fc2 + (size_t)c * 2048, fc2_b, out,
                                                  nullptr, out, M_TOK, 2048, 1024, 2048, 4096, 8);
    }
  }
}